// Round 2
// baseline (126.386 us; speedup 1.0000x reference)
//
#include <hip/hip_runtime.h>
#include <hip/hip_bf16.h>

typedef __attribute__((ext_vector_type(8))) short bf16x8;
typedef __attribute__((ext_vector_type(4))) float f32x4;
typedef __attribute__((ext_vector_type(4))) int   i32x4;
typedef __attribute__((ext_vector_type(2))) int   i32x2;

#define DEV static __device__ __forceinline__

DEV unsigned short f2bf(float f) {
  __hip_bfloat16 h = __float2bfloat16(f);
  return __builtin_bit_cast(unsigned short, h);
}
DEV int pack2(float a, float b) {
  return (int)f2bf(a) | ((int)f2bf(b) << 16);
}
DEV bf16x8 ldsFrag(const char* lds, int off) {
  i32x4 v = *(const i32x4*)(lds + off);
  return __builtin_bit_cast(bf16x8, v);
}

// B=4, C=4, N=512, T=256, K(P)=4, J(Q)=4
// Block = (bc, p, n-tile of 128). Grid = 16*4*4 = 256 blocks, 512 threads.
// Stage A: tmp[n][u] = sum_m S_p[n0+n][m] * X[m][u]   (computed as tmp^T in acc)
// Stage B: y[n][t]   = sum_u tmp[n][u]   * T_q[t][u]  -> relu(y), relu(-y)
// Output: [B, 2*C*K*J = 128, N, T]; positive half ch = c*16+p*4+q, negative +64.
__global__ __launch_bounds__(512, 2) void stblis_fused(
    const float* __restrict__ x, const float* __restrict__ sw,
    const float* __restrict__ tw, float* __restrict__ out)
{
  constexpr int N = 512, T = 256;
  // LDS map: [0,32768)  Xt[u=256][m=64] bf16, row 128B, slot s=(m>>3)^(u&7)
  //          [32768,49152) sS[n=128][m=64] bf16, same swizzle
  //          [0,65536)  tmp[n=128][u=256] bf16, row 512B, slot s=(u>>3)^(n&7)  (aliases staging)
  __shared__ __align__(16) char lds[65536];

  const int tid  = threadIdx.x;
  const int lane = tid & 63;
  const int wid  = tid >> 6;
  const int l15  = lane & 15;
  const int l4   = lane >> 4;

  const int bx = blockIdx.x;
  const int nt = bx & 3;
  const int p  = (bx >> 2) & 3;
  const int bc = bx >> 4;        // b*4 + c
  const int n0 = nt * 128;

  const float* __restrict__ X = x  + (size_t)bc * (N * T);
  const float* __restrict__ S = sw + (size_t)p * (N * N) + (size_t)n0 * N;

  // ---------------- stage A ----------------
  const int wu = wid >> 1;   // u block (64)
  const int wn = wid & 1;    // n block (64)

  f32x4 acc[4][4];
#pragma unroll
  for (int i = 0; i < 4; i++)
#pragma unroll
    for (int j = 0; j < 4; j++) acc[i][j] = {0.f, 0.f, 0.f, 0.f};

  // staging assignment (per thread, fixed):
  const int xu  = tid & 255;   // X: u column; strips m8 = s*2 + (tid>>8)
  const int xmb = tid >> 8;    // 0/1
  const int sm8 = tid & 7;     // S: m-slot; rows n = (tid>>3) + s*64
  const int snb = tid >> 3;    // 0..63

  float xr[4][8];
  float sr[2][8];

  // prefetch chunk 0
#pragma unroll
  for (int s = 0; s < 4; s++) {
    const float* px = X + (size_t)((s * 2 + xmb) * 8) * T + xu;
#pragma unroll
    for (int r = 0; r < 8; r++) xr[s][r] = px[(size_t)r * T];
  }
#pragma unroll
  for (int s = 0; s < 2; s++) {
    const float* ps = S + (size_t)(snb + s * 64) * N + sm8 * 8;
#pragma unroll
    for (int r = 0; r < 8; r++) sr[s][r] = ps[r];
  }

  for (int kc = 0; kc < 8; kc++) {
    __syncthreads();   // previous chunk's frag reads done -> staging LDS reusable
    // write staged regs -> LDS (bf16, transposed for X, slot-XOR swizzled)
#pragma unroll
    for (int s = 0; s < 4; s++) {
      int m8 = s * 2 + xmb;
      i32x4 w;
      w[0] = pack2(xr[s][0], xr[s][1]); w[1] = pack2(xr[s][2], xr[s][3]);
      w[2] = pack2(xr[s][4], xr[s][5]); w[3] = pack2(xr[s][6], xr[s][7]);
      *(i32x4*)(lds + xu * 128 + ((m8 ^ (xu & 7)) << 4)) = w;
    }
#pragma unroll
    for (int s = 0; s < 2; s++) {
      int n = snb + s * 64;
      i32x4 w;
      w[0] = pack2(sr[s][0], sr[s][1]); w[1] = pack2(sr[s][2], sr[s][3]);
      w[2] = pack2(sr[s][4], sr[s][5]); w[3] = pack2(sr[s][6], sr[s][7]);
      *(i32x4*)(lds + 32768 + n * 128 + ((sm8 ^ (n & 7)) << 4)) = w;
    }
    __syncthreads();

    if (kc < 7) {  // prefetch next chunk; overlaps MFMA below
#pragma unroll
      for (int s = 0; s < 4; s++) {
        const float* px = X + (size_t)((kc + 1) * 64 + (s * 2 + xmb) * 8) * T + xu;
#pragma unroll
        for (int r = 0; r < 8; r++) xr[s][r] = px[(size_t)r * T];
      }
#pragma unroll
      for (int s = 0; s < 2; s++) {
        const float* ps = S + (size_t)(snb + s * 64) * N + (kc + 1) * 64 + sm8 * 8;
#pragma unroll
        for (int r = 0; r < 8; r++) sr[s][r] = ps[r];
      }
    }

#pragma unroll
    for (int ks = 0; ks < 2; ks++) {
      const int slot = ks * 4 + l4;   // m-slot 0..7
      bf16x8 af[4], bg[4];
#pragma unroll
      for (int uf = 0; uf < 4; uf++) {
        int u = wu * 64 + uf * 16 + l15;
        af[uf] = ldsFrag(lds, u * 128 + ((slot ^ (u & 7)) << 4));
      }
#pragma unroll
      for (int nf = 0; nf < 4; nf++) {
        int n = wn * 64 + nf * 16 + l15;
        bg[nf] = ldsFrag(lds, 32768 + n * 128 + ((slot ^ (n & 7)) << 4));
      }
#pragma unroll
      for (int uf = 0; uf < 4; uf++)
#pragma unroll
        for (int nf = 0; nf < 4; nf++)
          acc[uf][nf] = __builtin_amdgcn_mfma_f32_16x16x32_bf16(
              af[uf], bg[nf], acc[uf][nf], 0, 0, 0);
    }
  }

  // acc (tmp^T fragments) -> LDS tmp[n][u] bf16; C-frag regs are 4 consecutive u
  __syncthreads();
#pragma unroll
  for (int uf = 0; uf < 4; uf++)
#pragma unroll
    for (int nf = 0; nf < 4; nf++) {
      int u0 = wu * 64 + uf * 16 + l4 * 4;
      int n  = wn * 64 + nf * 16 + l15;
      i32x2 w;
      w[0] = pack2(acc[uf][nf][0], acc[uf][nf][1]);
      w[1] = pack2(acc[uf][nf][2], acc[uf][nf][3]);
      *(i32x2*)(lds + n * 512 + (((u0 >> 3) ^ (n & 7)) << 4) + (u0 & 7) * 2) = w;
    }
  __syncthreads();

  // ---------------- stage B ----------------
  const int q  = wid >> 1;
  const int nh = wid & 1;
  const float* __restrict__ Tq = tw + (size_t)q * (T * T);
  const int b = bc >> 2, c = bc & 3;
  const int ch = c * 16 + p * 4 + q;          // c*K*J + p*J + q  in [0,64)
  float* __restrict__ outP = out + ((size_t)(b * 128 + ch) * N + n0) * T;
  float* __restrict__ outN = outP + (size_t)64 * N * T;   // negative half: +64 channels

  for (int tc = 0; tc < 4; tc++) {
    f32x4 a2[4][4];
#pragma unroll
    for (int i = 0; i < 4; i++)
#pragma unroll
      for (int j = 0; j < 4; j++) a2[i][j] = {0.f, 0.f, 0.f, 0.f};

#pragma unroll
    for (int us = 0; us < 8; us++) {
      const int slot = us * 4 + l4;    // u-slot 0..31
      const int ulo  = slot * 8;
      bf16x8 af[4], bg[4];
#pragma unroll
      for (int nf = 0; nf < 4; nf++) {
        int n = nh * 64 + nf * 16 + l15;
        af[nf] = ldsFrag(lds, n * 512 + ((slot ^ (n & 7)) << 4));
      }
#pragma unroll
      for (int tf = 0; tf < 4; tf++) {
        int t = tc * 64 + tf * 16 + l15;
        const f32x4* pt = (const f32x4*)(Tq + (size_t)t * T + ulo);
        f32x4 A = pt[0], Bv = pt[1];
        i32x4 w;
        w[0] = pack2(A[0], A[1]);  w[1] = pack2(A[2], A[3]);
        w[2] = pack2(Bv[0], Bv[1]); w[3] = pack2(Bv[2], Bv[3]);
        bg[tf] = __builtin_bit_cast(bf16x8, w);
      }
#pragma unroll
      for (int nf = 0; nf < 4; nf++)
#pragma unroll
        for (int tf = 0; tf < 4; tf++)
          a2[nf][tf] = __builtin_amdgcn_mfma_f32_16x16x32_bf16(
              af[nf], bg[tf], a2[nf][tf], 0, 0, 0);
    }

    // dual-ReLU epilogue; 16-lane groups write contiguous 64B runs
#pragma unroll
    for (int nf = 0; nf < 4; nf++) {
#pragma unroll
      for (int tf = 0; tf < 4; tf++) {
        int t  = tc * 64 + tf * 16 + l15;
        int nb = nh * 64 + nf * 16 + l4 * 4;
#pragma unroll
        for (int r = 0; r < 4; r++) {
          float v = a2[nf][tf][r];
          size_t o = (size_t)(nb + r) * T + t;
          outP[o] = fmaxf(v, 0.f);
          outN[o] = fmaxf(-v, 0.f);
        }
      }
    }
  }
}

extern "C" void kernel_launch(void* const* d_in, const int* in_sizes, int n_in,
                              void* d_out, int out_size, void* d_ws, size_t ws_size,
                              hipStream_t stream) {
  (void)in_sizes; (void)n_in; (void)out_size; (void)d_ws; (void)ws_size;
  const float* x  = (const float*)d_in[0];
  const float* sw = (const float*)d_in[1];
  const float* tw = (const float*)d_in[2];
  float* out = (float*)d_out;
  stblis_fused<<<dim3(256), dim3(512), 0, stream>>>(x, sw, tw, out);
}